// Round 5
// baseline (325.759 us; speedup 1.0000x reference)
//
#include <hip/hip_runtime.h>
#include <math.h>

// BalNoisedTopK: loss = mean_i relu(1 + mean_j kth_max(s_i + Z_ij, excl y_i) - s_{i,y_i})
// s: (n, d) f32, y: (n,) i32, Z: (n, d, m) f32 (m innermost), out: scalar f32.
// K=5, m=8, eps=1.0 compile-time constants per the reference.
//
// Single fused kernel: grid = n*nchunks chunk-blocks. Each block computes its
// chunk's per-sample top-5 (float4 Z loads, branchless med3 insert network,
// butterfly merges). Last block of each row (per-row atomic counter) merges the
// row's candidates -> rloss[i]; last row overall (global counter) writes the
// batch mean. Counters are memset-to-0 on the stream each call (capture-legal).

#define KTOP 5
#define MSAMP 8
#define TPB 256
#define NCHUNKS 32

// v sorted ascending; v[0] = current 5th-largest. Branchless insert:
// new v[q] = median(x, v[q], v[q+1]) == clamp(x, v[q], v[q+1]) since v sorted.
__device__ __forceinline__ void topk_insert_bl(float (&v)[KTOP], float x) {
    float n0 = __builtin_amdgcn_fmed3f(x, v[0], v[1]);
    float n1 = __builtin_amdgcn_fmed3f(x, v[1], v[2]);
    float n2 = __builtin_amdgcn_fmed3f(x, v[2], v[3]);
    float n3 = __builtin_amdgcn_fmed3f(x, v[3], v[4]);
    float n4 = fmaxf(v[4], x);
    v[0] = n0; v[1] = n1; v[2] = n2; v[3] = n3; v[4] = n4;
}

__global__ __launch_bounds__(TPB) void fused_topk(
    const float* __restrict__ s, const int* __restrict__ y,
    const float* __restrict__ Z, float* __restrict__ cand,
    float* __restrict__ rloss, int* __restrict__ rcnt, int* __restrict__ gcnt,
    float* __restrict__ out, int n, int d, int nchunks, int chunk)
{
    const int i = blockIdx.x / nchunks;
    const int c = blockIdx.x % nchunks;
    const int e0 = c * chunk;                 // chunk is 128-aligned
    const int e1 = min(e0 + chunk, d);
    const int yi = y[i];

    const int t = threadIdx.x;
    const int h = t & 1;            // sample half: owns samples h*4 .. h*4+3
    const int eofs = t >> 1;        // 0..127: element offset

    const float* __restrict__ srow = s + (size_t)i * d;
    const float* __restrict__ zrow = Z + (size_t)i * d * MSAMP;

    float v[4][KTOP];
    #pragma unroll
    for (int l = 0; l < 4; ++l)
        #pragma unroll
        for (int q = 0; q < KTOP; ++q) v[l][q] = -INFINITY;

    // 128 elements x 8 samples per block-iter; each lane: one float4 of Z
    // (16B/lane, wave = 1KB contiguous) + one s dword shared by lane pairs.
    #pragma unroll 4
    for (int e = e0 + eofs; e < e1; e += TPB / 2) {
        float sv = srow[e];
        const float4 z = *(const float4*)(zrow + (size_t)e * MSAMP + h * 4);
        sv = (e == yi) ? -INFINITY : sv;      // -inf + z = -inf: excluded
        topk_insert_bl(v[0], sv + z.x);
        topk_insert_bl(v[1], sv + z.y);
        topk_insert_bl(v[2], sv + z.z);
        topk_insert_bl(v[3], sv + z.w);
    }

    // Butterfly over offsets 2..32 (bit0 preserved -> same sample half).
    // Afterwards every lane holds its parity-group's merged 4 lists.
    #pragma unroll
    for (int off = 2; off <= 32; off <<= 1) {
        #pragma unroll
        for (int l = 0; l < 4; ++l) {
            float o[KTOP];
            #pragma unroll
            for (int q = 0; q < KTOP; ++q) o[q] = __shfl_xor(v[l][q], off, 64);
            #pragma unroll
            for (int q = 0; q < KTOP; ++q) topk_insert_bl(v[l], o[q]);
        }
    }

    __shared__ float lds[TPB / 64][MSAMP][KTOP];
    __shared__ float kj[MSAMP];
    __shared__ int lastflag;
    const int wave = t >> 6;
    const int lane = t & 63;
    if (lane < 2) {
        #pragma unroll
        for (int l = 0; l < 4; ++l)
            #pragma unroll
            for (int q = 0; q < KTOP; ++q) lds[wave][lane * 4 + l][q] = v[l][q];
    }
    __syncthreads();

    if (t < MSAMP) {
        float f[KTOP];
        #pragma unroll
        for (int q = 0; q < KTOP; ++q) f[q] = lds[0][t][q];
        #pragma unroll
        for (int w = 1; w < TPB / 64; ++w)
            #pragma unroll
            for (int q = 0; q < KTOP; ++q) topk_insert_bl(f, lds[w][t][q]);
        float* cp = cand + (((size_t)i * nchunks + c) * MSAMP + t) * KTOP;
        #pragma unroll
        for (int q = 0; q < KTOP; ++q) cp[q] = f[q];
    }
    __threadfence();                 // release cand writes device-wide
    __syncthreads();

    if (t == 0) {
        int old = atomicAdd(&rcnt[i], 1);
        lastflag = (old == nchunks - 1);
    }
    __syncthreads();
    if (!lastflag) return;
    __threadfence();                 // acquire: all row-i cand now visible

    // ---- This block is the last for row i: merge the row's candidates. ----
    float f2[KTOP];
    #pragma unroll
    for (int q = 0; q < KTOP; ++q) f2[q] = -INFINITY;
    const int j = t & 7;
    for (int c2 = t >> 3; c2 < nchunks; c2 += TPB / MSAMP) {
        const float* p = cand + (((size_t)i * nchunks + c2) * MSAMP + j) * KTOP;
        #pragma unroll
        for (int q = 0; q < KTOP; ++q) topk_insert_bl(f2, p[q]);
    }
    #pragma unroll
    for (int off = 8; off <= 32; off <<= 1) {   // preserves t&7
        float o[KTOP];
        #pragma unroll
        for (int q = 0; q < KTOP; ++q) o[q] = __shfl_xor(f2[q], off, 64);
        #pragma unroll
        for (int q = 0; q < KTOP; ++q) topk_insert_bl(f2, o[q]);
    }
    __syncthreads();                 // lds reuse
    if (lane < MSAMP) {
        #pragma unroll
        for (int q = 0; q < KTOP; ++q) lds[wave][lane][q] = f2[q];
    }
    __syncthreads();
    if (t < MSAMP) {
        float f3[KTOP];
        #pragma unroll
        for (int q = 0; q < KTOP; ++q) f3[q] = lds[0][t][q];
        #pragma unroll
        for (int w = 1; w < TPB / 64; ++w)
            #pragma unroll
            for (int q = 0; q < KTOP; ++q) topk_insert_bl(f3, lds[w][t][q]);
        kj[t] = f3[0];               // exact 5th-largest for (i, sample t)
    }
    __syncthreads();

    if (t == 0) {
        float sum = 0.0f;
        #pragma unroll
        for (int jj = 0; jj < MSAMP; ++jj) sum += kj[jj];
        float kth_smooth = sum * (1.0f / (float)MSAMP);
        float sy = s[(size_t)i * d + yi];
        rloss[i] = fmaxf(1.0f + kth_smooth - sy, 0.0f);
        __threadfence();             // release rloss before global count
        int old2 = atomicAdd(gcnt, 1);
        if (old2 == n - 1) {         // last row finished: batch mean
            __threadfence();
            float acc = 0.0f;
            for (int r = 0; r < n; ++r) acc += rloss[r];
            out[0] = acc / (float)n;
        }
    }
}

extern "C" void kernel_launch(void* const* d_in, const int* in_sizes, int n_in,
                              void* d_out, int out_size, void* d_ws, size_t ws_size,
                              hipStream_t stream) {
    const float* s = (const float*)d_in[0];
    const int*   y = (const int*)d_in[1];
    const float* Z = (const float*)d_in[2];
    float* out = (float*)d_out;

    const int n = in_sizes[1];
    const int d = in_sizes[0] / n;

    // ws layout: [rcnt: n ints][gcnt: 1 int][rloss: n f32][cand]
    char* ws = (char*)d_ws;
    int*   rcnt  = (int*)ws;
    int*   gcnt  = rcnt + n;
    size_t off   = ((size_t)(n + 1) * sizeof(int) + 255) & ~(size_t)255;
    float* rloss = (float*)(ws + off);
    off += ((size_t)n * sizeof(float) + 255) & ~(size_t)255;
    float* cand  = (float*)(ws + off);

    int nchunks = NCHUNKS;
    while (nchunks > 1 &&
           off + (size_t)n * nchunks * MSAMP * KTOP * sizeof(float) > ws_size) {
        nchunks >>= 1;
    }
    int chunk = (d + nchunks - 1) / nchunks;
    chunk = (chunk + 127) & ~127;    // 128-aligned -> aligned float4 segments

    hipMemsetAsync(rcnt, 0, (size_t)(n + 1) * sizeof(int), stream);
    hipLaunchKernelGGL(fused_topk, dim3(n * nchunks), dim3(TPB), 0, stream,
                       s, y, Z, cand, rloss, rcnt, gcnt, out, n, d, nchunks, chunk);
}

// Round 6
// 46.938 us; speedup vs baseline: 6.9401x; 6.9401x over previous
//
#include <hip/hip_runtime.h>
#include <math.h>

// BalNoisedTopK: loss = mean_i relu(1 + mean_j kth_max(s_i + Z_ij, excl y_i) - s_{i,y_i})
// s: (n, d) f32, y: (n,) i32, Z: (n, d, m) f32 (m innermost), out: scalar f32.
// K=5, m=8, eps=1.0 compile-time constants per the reference.
//
// Three kernels, no fences/atomics (R5's per-block __threadfence() fusion
// caused L2-invalidate storms: 508us, VALUBusy 4%). Stage 1 uses float4 Z
// loads: lane t owns element e0+(t>>1), samples (t&1)*4..+3 -> wave reads
// 1KB contiguous aligned Z per iteration.

#define KTOP 5
#define MSAMP 8
#define TPB 256
#define NCHUNKS 32

// v sorted ascending; v[0] = current 5th-largest. Branchless insert:
// new v[q] = median(x, v[q], v[q+1]) == clamp(x, v[q], v[q+1]) since v sorted.
__device__ __forceinline__ void topk_insert_bl(float (&v)[KTOP], float x) {
    float n0 = __builtin_amdgcn_fmed3f(x, v[0], v[1]);
    float n1 = __builtin_amdgcn_fmed3f(x, v[1], v[2]);
    float n2 = __builtin_amdgcn_fmed3f(x, v[2], v[3]);
    float n3 = __builtin_amdgcn_fmed3f(x, v[3], v[4]);
    float n4 = fmaxf(v[4], x);
    v[0] = n0; v[1] = n1; v[2] = n2; v[3] = n3; v[4] = n4;
}

__global__ __launch_bounds__(TPB) void topk_partial(
    const float* __restrict__ s, const int* __restrict__ y,
    const float* __restrict__ Z, float* __restrict__ cand,
    int d, int nchunks, int chunk)
{
    const int i = blockIdx.x / nchunks;
    const int c = blockIdx.x % nchunks;
    const int e0 = c * chunk;                 // chunk is 128-aligned
    const int e1 = min(e0 + chunk, d);
    const int yi = y[i];

    const int t = threadIdx.x;
    const int h = t & 1;            // sample half: owns samples h*4 .. h*4+3
    const int eofs = t >> 1;        // 0..127: element offset

    const float* __restrict__ srow = s + (size_t)i * d;
    const float* __restrict__ zrow = Z + (size_t)i * d * MSAMP;

    float v[4][KTOP];
    #pragma unroll
    for (int l = 0; l < 4; ++l)
        #pragma unroll
        for (int q = 0; q < KTOP; ++q) v[l][q] = -INFINITY;

    // 128 elements x 8 samples per block-iter; each lane: one float4 of Z
    // (16B/lane, wave = 1KB contiguous) + one s dword shared by lane pairs.
    #pragma unroll 4
    for (int e = e0 + eofs; e < e1; e += TPB / 2) {
        float sv = srow[e];
        const float4 z = *(const float4*)(zrow + (size_t)e * MSAMP + h * 4);
        sv = (e == yi) ? -INFINITY : sv;      // -inf + z = -inf: excluded
        topk_insert_bl(v[0], sv + z.x);
        topk_insert_bl(v[1], sv + z.y);
        topk_insert_bl(v[2], sv + z.z);
        topk_insert_bl(v[3], sv + z.w);
    }

    // Butterfly over offsets 2..32 (bit0 = sample half preserved). Afterwards
    // every lane holds its parity-group's 4 merged lists (all 32 eofs of wave).
    #pragma unroll
    for (int off = 2; off <= 32; off <<= 1) {
        #pragma unroll
        for (int l = 0; l < 4; ++l) {
            float o[KTOP];
            #pragma unroll
            for (int q = 0; q < KTOP; ++q) o[q] = __shfl_xor(v[l][q], off, 64);
            #pragma unroll
            for (int q = 0; q < KTOP; ++q) topk_insert_bl(v[l], o[q]);
        }
    }

    __shared__ float lds[TPB / 64][MSAMP][KTOP];
    const int wave = t >> 6;
    const int lane = t & 63;
    if (lane < 2) {                  // lane h holds samples h*4..h*4+3
        #pragma unroll
        for (int l = 0; l < 4; ++l)
            #pragma unroll
            for (int q = 0; q < KTOP; ++q) lds[wave][lane * 4 + l][q] = v[l][q];
    }
    __syncthreads();

    if (t < MSAMP) {
        float f[KTOP];
        #pragma unroll
        for (int q = 0; q < KTOP; ++q) f[q] = lds[0][t][q];
        #pragma unroll
        for (int w = 1; w < TPB / 64; ++w)
            #pragma unroll
            for (int q = 0; q < KTOP; ++q) topk_insert_bl(f, lds[w][t][q]);
        float* out = cand + (((size_t)i * nchunks + c) * MSAMP + t) * KTOP;
        #pragma unroll
        for (int q = 0; q < KTOP; ++q) out[q] = f[q];
    }
}

// One block per row i; 256 threads: thread t -> chunk c = t>>3, sample j = t&7.
// Merges chunk candidates (butterfly over c within wave, LDS across waves),
// averages kth over samples, writes the row hinge loss.
__global__ __launch_bounds__(TPB) void row_loss(
    const float* __restrict__ s, const int* __restrict__ y,
    const float* __restrict__ cand, float* __restrict__ rloss,
    int d, int nchunks)
{
    const int i = blockIdx.x;
    const int t = threadIdx.x;
    const int j = t & 7;
    const int wave = t >> 6;
    const int lane = t & 63;

    float v[KTOP];
    #pragma unroll
    for (int q = 0; q < KTOP; ++q) v[q] = -INFINITY;

    for (int c = t >> 3; c < nchunks; c += TPB / MSAMP) {
        const float* p = cand + (((size_t)i * nchunks + c) * MSAMP + j) * KTOP;
        #pragma unroll
        for (int q = 0; q < KTOP; ++q) topk_insert_bl(v, p[q]);
    }

    // Merge across the 8 chunk-slots sharing sample j inside this wave.
    #pragma unroll
    for (int off = 8; off <= 32; off <<= 1) {
        float o[KTOP];
        #pragma unroll
        for (int q = 0; q < KTOP; ++q) o[q] = __shfl_xor(v[q], off, 64);
        #pragma unroll
        for (int q = 0; q < KTOP; ++q) topk_insert_bl(v, o[q]);
    }

    __shared__ float lds[TPB / 64][MSAMP][KTOP];
    __shared__ float kth_j[MSAMP];
    if (lane < MSAMP) {
        #pragma unroll
        for (int q = 0; q < KTOP; ++q) lds[wave][lane][q] = v[q];
    }
    __syncthreads();

    if (t < MSAMP) {
        float f[KTOP];
        #pragma unroll
        for (int q = 0; q < KTOP; ++q) f[q] = lds[0][t][q];
        #pragma unroll
        for (int w = 1; w < TPB / 64; ++w)
            #pragma unroll
            for (int q = 0; q < KTOP; ++q) topk_insert_bl(f, lds[w][t][q]);
        kth_j[t] = f[0];                 // exact 5th-largest for (i, j=t)
    }
    __syncthreads();

    if (t == 0) {
        float sum = 0.0f;
        #pragma unroll
        for (int jj = 0; jj < MSAMP; ++jj) sum += kth_j[jj];
        float kth_smooth = sum * (1.0f / (float)MSAMP);
        float sy = s[(size_t)i * d + y[i]];
        rloss[i] = fmaxf(1.0f + kth_smooth - sy, 0.0f);
    }
}

__global__ __launch_bounds__(64) void mean_loss(
    const float* __restrict__ rloss, float* __restrict__ out, int n)
{
    const int t = threadIdx.x;
    float x = (t < n) ? rloss[t] : 0.0f;
    #pragma unroll
    for (int off = 32; off >= 1; off >>= 1) x += __shfl_xor(x, off, 64);
    if (t == 0) out[0] = x / (float)n;
}

extern "C" void kernel_launch(void* const* d_in, const int* in_sizes, int n_in,
                              void* d_out, int out_size, void* d_ws, size_t ws_size,
                              hipStream_t stream) {
    const float* s = (const float*)d_in[0];
    const int*   y = (const int*)d_in[1];
    const float* Z = (const float*)d_in[2];
    float* out = (float*)d_out;

    const int n = in_sizes[1];
    const int d = in_sizes[0] / n;

    int nchunks = NCHUNKS;
    while (nchunks > 1 &&
           (size_t)n * nchunks * MSAMP * KTOP * sizeof(float) + n * sizeof(float)
               > ws_size) {
        nchunks >>= 1;
    }
    int chunk = (d + nchunks - 1) / nchunks;
    chunk = (chunk + 127) & ~127;    // 128-aligned -> aligned float4 segments
    float* cand  = (float*)d_ws;
    float* rloss = cand + (size_t)n * nchunks * MSAMP * KTOP;

    hipLaunchKernelGGL(topk_partial, dim3(n * nchunks), dim3(TPB), 0, stream,
                       s, y, Z, cand, d, nchunks, chunk);
    hipLaunchKernelGGL(row_loss, dim3(n), dim3(TPB), 0, stream,
                       s, y, cand, rloss, d, nchunks);
    hipLaunchKernelGGL(mean_loss, dim3(1), dim3(64), 0, stream,
                       rloss, out, n);
}

// Round 7
// 44.186 us; speedup vs baseline: 7.3725x; 1.0623x over previous
//
#include <hip/hip_runtime.h>
#include <math.h>

// BalNoisedTopK: loss = mean_i relu(1 + mean_j kth_max(s_i + Z_ij, excl y_i) - s_{i,y_i})
// s: (n, d) f32, y: (n,) i32, Z: (n, d, m) f32 (m innermost), out: scalar f32.
// K=5, m=8, eps=1.0 compile-time constants per the reference.
//
// R4 base (dword Z loads, 3 kernels, no fences) + single change: s-chunk is
// staged into LDS once per block (coalesced float4), removing the 32B-useful
// per-iteration s gather from the hot loop (halves hot-loop VMEM insts).

#define KTOP 5
#define MSAMP 8
#define TPB 256
#define NCHUNKS 32
#define SLDS 3200   // max staged chunk elements (nchunks=32 -> chunk=3136)

// v sorted ascending; v[0] = current 5th-largest. Branchless insert:
// new v[q] = median(x, v[q], v[q+1]) == clamp(x, v[q], v[q+1]) since v sorted.
__device__ __forceinline__ void topk_insert_bl(float (&v)[KTOP], float x) {
    float n0 = __builtin_amdgcn_fmed3f(x, v[0], v[1]);
    float n1 = __builtin_amdgcn_fmed3f(x, v[1], v[2]);
    float n2 = __builtin_amdgcn_fmed3f(x, v[2], v[3]);
    float n3 = __builtin_amdgcn_fmed3f(x, v[3], v[4]);
    float n4 = fmaxf(v[4], x);
    v[0] = n0; v[1] = n1; v[2] = n2; v[3] = n3; v[4] = n4;
}

__global__ __launch_bounds__(TPB) void topk_partial(
    const float* __restrict__ s, const int* __restrict__ y,
    const float* __restrict__ Z, float* __restrict__ cand,
    int d, int nchunks, int chunk)
{
    const int i = blockIdx.x / nchunks;
    const int c = blockIdx.x % nchunks;
    const int e0 = c * chunk;                 // chunk is 32-aligned
    const int e1 = min(e0 + chunk, d);
    const int yi = y[i];

    const int t = threadIdx.x;
    const int j = t & 7;          // sample owned by this lane
    const int eofs = t >> 3;      // 0..31: element offset within block stride

    const float* __restrict__ srow = s + (size_t)i * d;
    const float* __restrict__ zrow = Z + (size_t)i * d * MSAMP;

    __shared__ __align__(16) float s_lds[SLDS];
    const int clen = e1 - e0;                 // may be <= 0 for trailing blocks
    const bool use_lds = (chunk <= SLDS);     // grid-uniform
    if (use_lds) {
        const int nv4 = clen > 0 ? (clen >> 2) : 0;
        for (int w = t; w < nv4; w += TPB) {  // srow+e0 is 128B-aligned
            float4 vv = *(const float4*)(srow + e0 + (size_t)w * 4);
            *(float4*)(s_lds + w * 4) = vv;
        }
        for (int w = (nv4 << 2) + t; w < clen; w += TPB)
            s_lds[w] = srow[e0 + w];
        __syncthreads();
    }

    float v[KTOP];
    #pragma unroll
    for (int q = 0; q < KTOP; ++q) v[q] = -INFINITY;

    // Block covers 32 elements x 8 samples per iteration; the wave's 64 Z
    // loads are one aligned 256B segment. s comes from LDS (8-lane broadcast).
    if (use_lds) {
        #pragma unroll 8
        for (int e = e0 + eofs; e < e1; e += 32) {
            float sv = s_lds[e - e0];
            float z  = zrow[(size_t)e * MSAMP + j];
            float x  = (e == yi) ? -INFINITY : (sv + z);
            topk_insert_bl(v, x);
        }
    } else {                                   // fallback: global s gather
        #pragma unroll 8
        for (int e = e0 + eofs; e < e1; e += 32) {
            float sv = srow[e];
            float z  = zrow[(size_t)e * MSAMP + j];
            float x  = (e == yi) ? -INFINITY : (sv + z);
            topk_insert_bl(v, x);
        }
    }

    // Butterfly merge across the 8 lanes that share sample j (xor 8/16/32
    // preserves t&7). Afterwards every lane holds its wave's per-sample top5.
    #pragma unroll
    for (int off = 8; off <= 32; off <<= 1) {
        float o[KTOP];
        #pragma unroll
        for (int q = 0; q < KTOP; ++q) o[q] = __shfl_xor(v[q], off, 64);
        #pragma unroll
        for (int q = 0; q < KTOP; ++q) topk_insert_bl(v, o[q]);
    }

    __shared__ float lds[TPB / 64][MSAMP][KTOP];
    const int wave = t >> 6;
    const int lane = t & 63;
    if (lane < MSAMP) {
        #pragma unroll
        for (int q = 0; q < KTOP; ++q) lds[wave][lane][q] = v[q];
    }
    __syncthreads();

    if (t < MSAMP) {
        float f[KTOP];
        #pragma unroll
        for (int q = 0; q < KTOP; ++q) f[q] = lds[0][t][q];
        #pragma unroll
        for (int w = 1; w < TPB / 64; ++w)
            #pragma unroll
            for (int q = 0; q < KTOP; ++q) topk_insert_bl(f, lds[w][t][q]);
        float* out = cand + (((size_t)i * nchunks + c) * MSAMP + t) * KTOP;
        #pragma unroll
        for (int q = 0; q < KTOP; ++q) out[q] = f[q];
    }
}

// One block per row i; 256 threads: thread t -> chunk c = t>>3, sample j = t&7.
// Merges chunk candidates (butterfly over c within wave, LDS across waves),
// averages kth over samples, writes the row hinge loss.
__global__ __launch_bounds__(TPB) void row_loss(
    const float* __restrict__ s, const int* __restrict__ y,
    const float* __restrict__ cand, float* __restrict__ rloss,
    int d, int nchunks)
{
    const int i = blockIdx.x;
    const int t = threadIdx.x;
    const int j = t & 7;
    const int wave = t >> 6;
    const int lane = t & 63;

    float v[KTOP];
    #pragma unroll
    for (int q = 0; q < KTOP; ++q) v[q] = -INFINITY;

    for (int c = t >> 3; c < nchunks; c += TPB / MSAMP) {
        const float* p = cand + (((size_t)i * nchunks + c) * MSAMP + j) * KTOP;
        #pragma unroll
        for (int q = 0; q < KTOP; ++q) topk_insert_bl(v, p[q]);
    }

    // Merge across the 8 chunk-slots sharing sample j inside this wave.
    #pragma unroll
    for (int off = 8; off <= 32; off <<= 1) {
        float o[KTOP];
        #pragma unroll
        for (int q = 0; q < KTOP; ++q) o[q] = __shfl_xor(v[q], off, 64);
        #pragma unroll
        for (int q = 0; q < KTOP; ++q) topk_insert_bl(v, o[q]);
    }

    __shared__ float lds[TPB / 64][MSAMP][KTOP];
    __shared__ float kth_j[MSAMP];
    if (lane < MSAMP) {
        #pragma unroll
        for (int q = 0; q < KTOP; ++q) lds[wave][lane][q] = v[q];
    }
    __syncthreads();

    if (t < MSAMP) {
        float f[KTOP];
        #pragma unroll
        for (int q = 0; q < KTOP; ++q) f[q] = lds[0][t][q];
        #pragma unroll
        for (int w = 1; w < TPB / 64; ++w)
            #pragma unroll
            for (int q = 0; q < KTOP; ++q) topk_insert_bl(f, lds[w][t][q]);
        kth_j[t] = f[0];                 // exact 5th-largest for (i, j=t)
    }
    __syncthreads();

    if (t == 0) {
        float sum = 0.0f;
        #pragma unroll
        for (int jj = 0; jj < MSAMP; ++jj) sum += kth_j[jj];
        float kth_smooth = sum * (1.0f / (float)MSAMP);
        float sy = s[(size_t)i * d + y[i]];
        rloss[i] = fmaxf(1.0f + kth_smooth - sy, 0.0f);
    }
}

__global__ __launch_bounds__(64) void mean_loss(
    const float* __restrict__ rloss, float* __restrict__ out, int n)
{
    const int t = threadIdx.x;
    float x = (t < n) ? rloss[t] : 0.0f;
    #pragma unroll
    for (int off = 32; off >= 1; off >>= 1) x += __shfl_xor(x, off, 64);
    if (t == 0) out[0] = x / (float)n;
}

extern "C" void kernel_launch(void* const* d_in, const int* in_sizes, int n_in,
                              void* d_out, int out_size, void* d_ws, size_t ws_size,
                              hipStream_t stream) {
    const float* s = (const float*)d_in[0];
    const int*   y = (const int*)d_in[1];
    const float* Z = (const float*)d_in[2];
    float* out = (float*)d_out;

    const int n = in_sizes[1];
    const int d = in_sizes[0] / n;

    int nchunks = NCHUNKS;
    while (nchunks > 1 &&
           (size_t)n * nchunks * MSAMP * KTOP * sizeof(float) + n * sizeof(float)
               > ws_size) {
        nchunks >>= 1;
    }
    int chunk = (d + nchunks - 1) / nchunks;
    chunk = (chunk + 31) & ~31;           // 32-aligned -> aligned Z segments
    float* cand  = (float*)d_ws;
    float* rloss = cand + (size_t)n * nchunks * MSAMP * KTOP;

    hipLaunchKernelGGL(topk_partial, dim3(n * nchunks), dim3(TPB), 0, stream,
                       s, y, Z, cand, d, nchunks, chunk);
    hipLaunchKernelGGL(row_loss, dim3(n), dim3(TPB), 0, stream,
                       s, y, cand, rloss, d, nchunks);
    hipLaunchKernelGGL(mean_loss, dim3(1), dim3(64), 0, stream,
                       rloss, out, n);
}